// Round 4
// baseline (11308.260 us; speedup 1.0000x reference)
//
#include <hip/hip_runtime.h>
#include <hip/hip_fp16.h>

#define BB 128
#define II 64
#define SS 2048
#define HH 128
#define GG 512   // 4*H
#define OO 64
#define TT 32    // x time-tile width

typedef _Float16 f16x2 __attribute__((ext_vector_type(2)));
union F4H { float4 f4; f16x2 h[4]; };

__device__ __forceinline__ f16x2 pack2(float a, float b) {
    f16x2 r; r.x = (_Float16)a; r.y = (_Float16)b; return r;
}

__device__ __forceinline__ float dot2(f16x2 w, f16x2 v, float c) {
#if __has_builtin(__builtin_amdgcn_fdot2)
    return __builtin_amdgcn_fdot2(w, v, c, false);
#else
    return fmaf((float)w.x, (float)v.x, fmaf((float)w.y, (float)v.y, c));
#endif
}

__device__ __forceinline__ float sigm(float v) {
    return __builtin_amdgcn_rcpf(1.0f + __expf(-v));
}
__device__ __forceinline__ float tanh_f(float v) {
    float a = fabsf(v);
    float e = __expf(-2.0f * a);
    float r = (1.0f - e) * __builtin_amdgcn_rcpf(1.0f + e);
    return v < 0.0f ? -r : r;
}

// 64 blocks x 512 threads: each block owns TWO batch elements (b0,b1) whose
// LSTM phases are SKEWED half a step so every barrier interval contains the
// heavy dot-phase of one batch and the light phase of the other:
//   i1: A0(t) | C1(t-1)            i3: C0(t) | A1(t)
//   i2: B0(t) | D1(t-1) | proj0    i4: D0(t) | B1(t)  | proj1
// Weights (registers + LDS) are shared by both batches; barriers per
// batch-step drop 4 -> 2, and the paired independent dependence chains fill
// each other's LDS/issue stalls (R1 measured ~3800 stall cyc of 5100/step:
// 1 block/CU + lockstep waves had nothing to hide latency with).
__global__ void
__attribute__((amdgpu_flat_work_group_size(512, 512)))
__attribute__((amdgpu_waves_per_eu(2, 2)))
nlstm_scan(
    const float* __restrict__ x,
    const float* __restrict__ Wx_out, const float* __restrict__ Wh_out,
    const float* __restrict__ b_out,
    const float* __restrict__ Wx_in, const float* __restrict__ Wh_in,
    const float* __restrict__ b_in,
    const float* __restrict__ W_lin, const float* __restrict__ b_lin,
    float* __restrict__ out)
{
    const int blk = blockIdx.x;
    const int b0  = 2 * blk;
    const int b1  = 2 * blk + 1;
    const int j   = threadIdx.x;

    // Wx_out fp16, chunk-major: chunk c (k=8c..8c+8) of column j at wxf[c*512+j].
    __shared__ __align__(16) float4 wxf[8 * 512];          // 64 KB
    // W_lin fp16, chunk-major padded: chunk c of row n at wlf[c*66+n].
    __shared__ __align__(16) float4 wlf[16 * 66];          // 16.5 KB
    // x time-tiles per batch, double-buffered, +1 pad kills column-read conflicts
    __shared__ float xt0[2][II][TT + 1];                   // 16.9 KB
    __shared__ float xt1[2][II][TT + 1];                   // 16.9 KB
    __shared__ __align__(16) f16x2 xb0[2][II / 2];         // b0 x_t fp16, dbuf
    __shared__ __align__(16) f16x2 xb1[II / 2];            // b1 x_t fp16
    __shared__ __align__(16) f16x2 hb0[HH / 2], hb1[HH / 2];
    __shared__ __align__(16) f16x2 xib0[HH / 2], hib0[HH / 2];
    __shared__ __align__(16) f16x2 xib1[HH / 2], hib1[HH / 2];
    __shared__ float cb0[HH], cnb0[HH], cb1[HH], cnb1[HH];
    __shared__ float actO0[GG], actI0[GG], actO1[GG], actI1[GG];

    // ---- register-resident fp16 weights (column j), shared by both batches ----
    f16x2 who[HH / 2];   // Wh_out col j
    f16x2 wxi[HH / 2];   // Wx_in  col j
    f16x2 whi[HH / 2];   // Wh_in  col j
#pragma unroll
    for (int m = 0; m < HH / 2; ++m)
        who[m] = pack2(Wh_out[(2 * m) * GG + j], Wh_out[(2 * m + 1) * GG + j]);
#pragma unroll
    for (int m = 0; m < HH / 2; ++m)
        wxi[m] = pack2(Wx_in[(2 * m) * GG + j], Wx_in[(2 * m + 1) * GG + j]);
#pragma unroll
    for (int m = 0; m < HH / 2; ++m)
        whi[m] = pack2(Wh_in[(2 * m) * GG + j], Wh_in[(2 * m + 1) * GG + j]);

    const float bo = b_out[j];
    const float bi = b_in[j];
    // projection: 4 threads per output row, threads 256..511 only
    const int   pn = (j - 256) >> 2;   // 0..63 (valid when j>=256)
    const int   ps = j & 3;            // chunk group
    const float bl = (j >= 256) ? b_lin[pn] : 0.f;

    // Wx_out -> LDS fp16 (thread j converts its own column)
#pragma unroll
    for (int c = 0; c < 8; ++c) {
        F4H u;
#pragma unroll
        for (int q = 0; q < 4; ++q)
            u.h[q] = pack2(Wx_out[(8 * c + 2 * q) * GG + j],
                           Wx_out[(8 * c + 2 * q + 1) * GG + j]);
        wxf[c * 512 + j] = u.f4;
    }
    // W_lin -> LDS fp16 (1024 chunks, 2 per thread)
#pragma unroll
    for (int r = 0; r < 2; ++r) {
        const int m = r * 512 + j;
        const int c = m >> 6, n = m & 63;
        F4H u;
#pragma unroll
        for (int q = 0; q < 4; ++q)
            u.h[q] = pack2(W_lin[n * HH + 8 * c + 2 * q],
                           W_lin[n * HH + 8 * c + 2 * q + 1]);
        wlf[c * 66 + n] = u.f4;
    }

    const float* xrow0 = x + (size_t)b0 * II * SS;
    const float* xrow1 = x + (size_t)b1 * II * SS;
    float* orow0 = out + (size_t)b0 * SS * OO;
    float* orow1 = out + (size_t)b1 * SS * OO;

    {   // tile 0 for both batches (512 float4 each, 1+1 per thread)
        const int row = j >> 3, tc = j & 7;
        const float4 v0 = *(const float4*)(xrow0 + (size_t)row * SS + 4 * tc);
        const float4 v1 = *(const float4*)(xrow1 + (size_t)row * SS + 4 * tc);
        float* d0 = &xt0[0][row][4 * tc];
        d0[0] = v0.x; d0[1] = v0.y; d0[2] = v0.z; d0[3] = v0.w;
        float* d1 = &xt1[0][row][4 * tc];
        d1[0] = v1.x; d1[1] = v1.y; d1[2] = v1.z; d1[3] = v1.w;
    }
    if (j < HH / 2) { hb0[j] = pack2(0.f, 0.f); hb1[j] = pack2(0.f, 0.f); }
    if (j < HH) { cb0[j] = 0.f; cnb0[j] = 0.f; cb1[j] = 0.f; cnb1[j] = 0.f; }
    if (j >= 256 && j < 288) {                 // initial xb0[0] pack (t=0)
        const int m = j - 256;
        xb0[0][m] = pack2(xrow0[(2 * m) * SS], xrow0[(2 * m + 1) * SS]);
    }
    __syncthreads();

    const float4* hb0_4 = (const float4*)hb0;   // 16 chunks
    const float4* hb1_4 = (const float4*)hb1;
    const float4* xi0_4 = (const float4*)xib0;
    const float4* hi0_4 = (const float4*)hib0;
    const float4* xi1_4 = (const float4*)xib1;
    const float4* hi1_4 = (const float4*)hib1;
    const float4* xb1_4 = (const float4*)xb1;

#pragma unroll 1
    for (int t = 0; t < SS; ++t) {
        const bool doTile = ((t & 31) == 30) && (t + 2 < SS);
        const int  Tn     = (t + 2) >> 5;

        // ================= i1: A0(t)  ||  C1(t-1) =================
        {
            const float4* x0c = (const float4*)xb0[t & 1];
            float a0 = 0.f, a1 = 0.f, a2 = 0.f, a3 = 0.f;
#pragma unroll
            for (int c = 0; c < 8; ++c) {
                F4H xu; xu.f4 = x0c[c];
                F4H wu; wu.f4 = wxf[c * 512 + j];
                a0 = dot2(wu.h[0], xu.h[0], a0);
                a1 = dot2(wu.h[1], xu.h[1], a1);
                a2 = dot2(wu.h[2], xu.h[2], a2);
                a3 = dot2(wu.h[3], xu.h[3], a3);
            }
#pragma unroll
            for (int c = 0; c < 16; ++c) {
                F4H hu; hu.f4 = hb0_4[c];
                a0 = dot2(who[4 * c + 0], hu.h[0], a0);
                a1 = dot2(who[4 * c + 1], hu.h[1], a1);
                a2 = dot2(who[4 * c + 2], hu.h[2], a2);
                a3 = dot2(who[4 * c + 3], hu.h[3], a3);
            }
            const float acc = (a0 + a1) + (a2 + a3) + bo;
            actO0[j] = (j < 384) ? sigm(acc) : tanh_f(acc);
        }
        if (t > 0) {   // C1(t-1): inner gates for b1
            float c0 = 0.f, c1 = 0.f, c2 = 0.f, c3 = 0.f;
#pragma unroll
            for (int c = 0; c < 16; ++c) {
                F4H xu; xu.f4 = xi1_4[c];
                c0 = dot2(wxi[4 * c + 0], xu.h[0], c0);
                c1 = dot2(wxi[4 * c + 1], xu.h[1], c1);
                c2 = dot2(wxi[4 * c + 2], xu.h[2], c2);
                c3 = dot2(wxi[4 * c + 3], xu.h[3], c3);
            }
#pragma unroll
            for (int c = 0; c < 16; ++c) {
                F4H hu; hu.f4 = hi1_4[c];
                c0 = dot2(whi[4 * c + 0], hu.h[0], c0);
                c1 = dot2(whi[4 * c + 1], hu.h[1], c1);
                c2 = dot2(whi[4 * c + 2], hu.h[2], c2);
                c3 = dot2(whi[4 * c + 3], hu.h[3], c3);
            }
            const float acc2 = (c0 + c1) + (c2 + c3) + bi;
            actI1[j] = (j < 384) ? sigm(acc2) : tanh_f(acc2);
        }
        __syncthreads();   // S1

        // ===== i2: B0(t) || D1(t-1) || proj0(t-1) + xb1 pack(t) + tile1 =====
        if (j < II) {                          // B0: x_in pairs
            xib0[j] = pack2(actO0[2 * j] * actO0[384 + 2 * j],
                            actO0[2 * j + 1] * actO0[384 + 2 * j + 1]);
        } else if (j < HH) {                   // B0: h_in pairs
            const int m = j - II;
            hib0[m] = pack2(actO0[HH + 2 * m] * cb0[2 * m],
                            actO0[HH + 2 * m + 1] * cb0[2 * m + 1]);
        } else if (j < 2 * HH) {               // D1(t-1)
            if (t > 0) {
                const int m = j - HH;
                const float cn_new = actI1[HH + m] * cnb1[m] + actI1[m] * actI1[384 + m];
                const float c_new  = actI1[2 * HH + m] * tanh_f(cn_new);
                const float h_new  = actO1[2 * HH + m] * tanh_f(c_new);
                cnb1[m] = cn_new;
                cb1[m]  = c_new;
                ((_Float16*)hb1)[m] = (_Float16)h_new;
            }
        } else {                               // proj0(t-1) on threads 256..511
            if (t > 0) {
                float p = 0.f;
#pragma unroll
                for (int q = 0; q < 4; ++q) {
                    const int c = 4 * ps + q;
                    F4H hu; hu.f4 = hb0_4[c];
                    F4H wu; wu.f4 = wlf[c * 66 + pn];
                    p = dot2(wu.h[0], hu.h[0], p);
                    p = dot2(wu.h[1], hu.h[1], p);
                    p = dot2(wu.h[2], hu.h[2], p);
                    p = dot2(wu.h[3], hu.h[3], p);
                }
                p += __shfl_down(p, 2, 4);
                p += __shfl_down(p, 1, 4);
                if (ps == 0) orow0[(size_t)(t - 1) * OO + pn] = p + bl;
            }
            if (j < 288) {                     // pack xb1 for step t
                const int m = j - 256;
                const int tb = (t >> 5) & 1, tt = t & 31;
                xb1[m] = pack2(xt1[tb][2 * m][tt], xt1[tb][2 * m + 1][tt]);
            }
        }
        if (doTile) {                          // prefetch next xt1 tile
            const int row = j >> 3, tc = j & 7;
            const float4 v = *(const float4*)(xrow1 + (size_t)row * SS + TT * Tn + 4 * tc);
            float* dst = &xt1[Tn & 1][row][4 * tc];
            dst[0] = v.x; dst[1] = v.y; dst[2] = v.z; dst[3] = v.w;
        }
        __syncthreads();   // S2

        // ================= i3: C0(t)  ||  A1(t) =================
        {
            float c0 = 0.f, c1 = 0.f, c2 = 0.f, c3 = 0.f;
#pragma unroll
            for (int c = 0; c < 16; ++c) {
                F4H xu; xu.f4 = xi0_4[c];
                c0 = dot2(wxi[4 * c + 0], xu.h[0], c0);
                c1 = dot2(wxi[4 * c + 1], xu.h[1], c1);
                c2 = dot2(wxi[4 * c + 2], xu.h[2], c2);
                c3 = dot2(wxi[4 * c + 3], xu.h[3], c3);
            }
#pragma unroll
            for (int c = 0; c < 16; ++c) {
                F4H hu; hu.f4 = hi0_4[c];
                c0 = dot2(whi[4 * c + 0], hu.h[0], c0);
                c1 = dot2(whi[4 * c + 1], hu.h[1], c1);
                c2 = dot2(whi[4 * c + 2], hu.h[2], c2);
                c3 = dot2(whi[4 * c + 3], hu.h[3], c3);
            }
            const float acc2 = (c0 + c1) + (c2 + c3) + bi;
            actI0[j] = (j < 384) ? sigm(acc2) : tanh_f(acc2);
        }
        {   // A1(t): outer gates for b1
            float a0 = 0.f, a1 = 0.f, a2 = 0.f, a3 = 0.f;
#pragma unroll
            for (int c = 0; c < 8; ++c) {
                F4H xu; xu.f4 = xb1_4[c];
                F4H wu; wu.f4 = wxf[c * 512 + j];
                a0 = dot2(wu.h[0], xu.h[0], a0);
                a1 = dot2(wu.h[1], xu.h[1], a1);
                a2 = dot2(wu.h[2], xu.h[2], a2);
                a3 = dot2(wu.h[3], xu.h[3], a3);
            }
#pragma unroll
            for (int c = 0; c < 16; ++c) {
                F4H hu; hu.f4 = hb1_4[c];
                a0 = dot2(who[4 * c + 0], hu.h[0], a0);
                a1 = dot2(who[4 * c + 1], hu.h[1], a1);
                a2 = dot2(who[4 * c + 2], hu.h[2], a2);
                a3 = dot2(who[4 * c + 3], hu.h[3], a3);
            }
            const float acc = (a0 + a1) + (a2 + a3) + bo;
            actO1[j] = (j < 384) ? sigm(acc) : tanh_f(acc);
        }
        __syncthreads();   // S3

        // ===== i4: D0(t) || B1(t) || proj1(t-1) + xb0 pack(t+1) + tile0 =====
        if (j < HH) {                          // D0(t)
            const float cn_new = actI0[HH + j] * cnb0[j] + actI0[j] * actI0[384 + j];
            const float c_new  = actI0[2 * HH + j] * tanh_f(cn_new);
            const float h_new  = actO0[2 * HH + j] * tanh_f(c_new);
            cnb0[j] = cn_new;
            cb0[j]  = c_new;
            ((_Float16*)hb0)[j] = (_Float16)h_new;
        } else if (j < HH + II) {              // B1: x_in pairs (m = j-128 < 64)
            const int m = j - HH;
            xib1[m] = pack2(actO1[2 * m] * actO1[384 + 2 * m],
                            actO1[2 * m + 1] * actO1[384 + 2 * m + 1]);
        } else if (j < 2 * HH) {               // B1: h_in pairs
            const int m = j - HH - II;
            hib1[m] = pack2(actO1[HH + 2 * m] * cb1[2 * m],
                            actO1[HH + 2 * m + 1] * cb1[2 * m + 1]);
        } else {                               // proj1(t-1) on threads 256..511
            if (t > 0) {
                float p = 0.f;
#pragma unroll
                for (int q = 0; q < 4; ++q) {
                    const int c = 4 * ps + q;
                    F4H hu; hu.f4 = hb1_4[c];
                    F4H wu; wu.f4 = wlf[c * 66 + pn];
                    p = dot2(wu.h[0], hu.h[0], p);
                    p = dot2(wu.h[1], hu.h[1], p);
                    p = dot2(wu.h[2], hu.h[2], p);
                    p = dot2(wu.h[3], hu.h[3], p);
                }
                p += __shfl_down(p, 2, 4);
                p += __shfl_down(p, 1, 4);
                if (ps == 0) orow1[(size_t)(t - 1) * OO + pn] = p + bl;
            }
            if (j < 288) {                     // pack xb0 for step t+1
                const int tn = t + 1;
                if (tn < SS) {
                    const int m = j - 256;
                    const int tb = (tn >> 5) & 1, tt = tn & 31;
                    xb0[tn & 1][m] = pack2(xt0[tb][2 * m][tt], xt0[tb][2 * m + 1][tt]);
                }
            }
        }
        if (doTile) {                          // prefetch next xt0 tile
            const int row = j >> 3, tc = j & 7;
            const float4 v = *(const float4*)(xrow0 + (size_t)row * SS + TT * Tn + 4 * tc);
            float* dst = &xt0[Tn & 1][row][4 * tc];
            dst[0] = v.x; dst[1] = v.y; dst[2] = v.z; dst[3] = v.w;
        }
        __syncthreads();   // S4
    }

    // ================= epilogue: finish b1 step SS-1, final projections =====
    {   // C1(SS-1) on all threads; proj0(SS-1) on threads 256..511
        float c0 = 0.f, c1 = 0.f, c2 = 0.f, c3 = 0.f;
#pragma unroll
        for (int c = 0; c < 16; ++c) {
            F4H xu; xu.f4 = xi1_4[c];
            c0 = dot2(wxi[4 * c + 0], xu.h[0], c0);
            c1 = dot2(wxi[4 * c + 1], xu.h[1], c1);
            c2 = dot2(wxi[4 * c + 2], xu.h[2], c2);
            c3 = dot2(wxi[4 * c + 3], xu.h[3], c3);
        }
#pragma unroll
        for (int c = 0; c < 16; ++c) {
            F4H hu; hu.f4 = hi1_4[c];
            c0 = dot2(whi[4 * c + 0], hu.h[0], c0);
            c1 = dot2(whi[4 * c + 1], hu.h[1], c1);
            c2 = dot2(whi[4 * c + 2], hu.h[2], c2);
            c3 = dot2(whi[4 * c + 3], hu.h[3], c3);
        }
        const float acc2 = (c0 + c1) + (c2 + c3) + bi;
        actI1[j] = (j < 384) ? sigm(acc2) : tanh_f(acc2);

        if (j >= 256) {                        // proj0(SS-1)
            float p = 0.f;
#pragma unroll
            for (int q = 0; q < 4; ++q) {
                const int c = 4 * ps + q;
                F4H hu; hu.f4 = hb0_4[c];
                F4H wu; wu.f4 = wlf[c * 66 + pn];
                p = dot2(wu.h[0], hu.h[0], p);
                p = dot2(wu.h[1], hu.h[1], p);
                p = dot2(wu.h[2], hu.h[2], p);
                p = dot2(wu.h[3], hu.h[3], p);
            }
            p += __shfl_down(p, 2, 4);
            p += __shfl_down(p, 1, 4);
            if (ps == 0) orow0[(size_t)(SS - 1) * OO + pn] = p + bl;
        }
    }
    __syncthreads();
    if (j < HH) {   // D1(SS-1)
        const float cn_new = actI1[HH + j] * cnb1[j] + actI1[j] * actI1[384 + j];
        const float c_new  = actI1[2 * HH + j] * tanh_f(cn_new);
        const float h_new  = actO1[2 * HH + j] * tanh_f(c_new);
        ((_Float16*)hb1)[j] = (_Float16)h_new;
    }
    __syncthreads();
    if (j >= 256) {  // proj1(SS-1)
        float p = 0.f;
#pragma unroll
        for (int q = 0; q < 4; ++q) {
            const int c = 4 * ps + q;
            F4H hu; hu.f4 = hb1_4[c];
            F4H wu; wu.f4 = wlf[c * 66 + pn];
            p = dot2(wu.h[0], hu.h[0], p);
            p = dot2(wu.h[1], hu.h[1], p);
            p = dot2(wu.h[2], hu.h[2], p);
            p = dot2(wu.h[3], hu.h[3], p);
        }
        p += __shfl_down(p, 2, 4);
        p += __shfl_down(p, 1, 4);
        if (ps == 0) orow1[(size_t)(SS - 1) * OO + pn] = p + bl;
    }
}

extern "C" void kernel_launch(void* const* d_in, const int* in_sizes, int n_in,
                              void* d_out, int out_size, void* d_ws, size_t ws_size,
                              hipStream_t stream) {
    (void)in_sizes; (void)n_in; (void)d_ws; (void)ws_size; (void)out_size;
    const float* x      = (const float*)d_in[0];
    const float* Wx_out = (const float*)d_in[1];
    const float* Wh_out = (const float*)d_in[2];
    const float* b_out  = (const float*)d_in[3];
    const float* Wx_in  = (const float*)d_in[4];
    const float* Wh_in  = (const float*)d_in[5];
    const float* b_in   = (const float*)d_in[6];
    const float* W_lin  = (const float*)d_in[7];
    const float* b_lin  = (const float*)d_in[8];
    float* out = (float*)d_out;

    nlstm_scan<<<dim3(BB / 2), dim3(512), 0, stream>>>(
        x, Wx_out, Wh_out, b_out, Wx_in, Wh_in, b_in, W_lin, b_lin, out);
}

// Round 5
// 7290.128 us; speedup vs baseline: 1.5512x; 1.5512x over previous
//
#include <hip/hip_runtime.h>

#define BB 128
#define II 64
#define SS 2048
#define HH 128
#define GG 512   // 4*H
#define OO 64
#define MB 16    // batch rows per block
#define NBLK (BB / MB)   // 8 blocks

typedef _Float16 f16x8 __attribute__((ext_vector_type(8)));
typedef _Float16 f16x2 __attribute__((ext_vector_type(2)));
typedef float    f32x4 __attribute__((ext_vector_type(4)));

#define MFMA16 __builtin_amdgcn_mfma_f32_16x16x32_f16

__device__ __forceinline__ float sigm(float v) {
    return __builtin_amdgcn_rcpf(1.0f + __expf(-v));
}
__device__ __forceinline__ float tanh_f(float v) {
    float a = fabsf(v);
    float e = __expf(-2.0f * a);
    float r = (1.0f - e) * __builtin_amdgcn_rcpf(1.0f + e);
    return v < 0.0f ? -r : r;
}

// 8 blocks x 512 threads; block owns 16 batch rows (M=16 MFMA).
// Wave w owns h-slice [16w,16w+16) of ALL FOUR gates (n-tiles 128g+16w),
// so i,f,o,g of a given h-column land in ONE wave's accumulators:
// x_in=i*g, h_in=f*c, and the full state update are wave-local register
// math (c,cn live in thread regs). 2 barriers/step. Weights are MFMA
// B-operands resident in AGPRs (free to read - kills the accvgpr tax that
// dominated the fdot2 kernels). x(t+1) is an L2-resident 4-dword gather
// hidden under the inner GEMM; projection overlaps the next A-phase.
__global__ void __launch_bounds__(512)
nlstm_mfma(const float* __restrict__ x,
           const float* __restrict__ Wx_out, const float* __restrict__ Wh_out,
           const float* __restrict__ b_out,
           const float* __restrict__ Wx_in, const float* __restrict__ Wh_in,
           const float* __restrict__ b_in,
           const float* __restrict__ W_lin, const float* __restrict__ b_lin,
           float* __restrict__ out)
{
    const int tid  = threadIdx.x;
    const int w    = tid >> 6;     // wave 0..7
    const int lane = tid & 63;
    const int l15  = lane & 15;
    const int l4   = lane >> 4;
    const int b0   = blockIdx.x * MB;

    // B-fragment stores: [kt][nt][lane][8 f16], one ds_read_b128 per frag.
    __shared__ __align__(16) _Float16 WXF[2][32][64][8];   // Wx_out frags, 64 KB
    __shared__ __align__(16) _Float16 WLF[4][4][64][8];    // W_lin^T frags, 16 KB
    // A-operand arrays, row-major [batch][k], 136-f16 row stride (16B-aligned,
    // 2-way-bank-free for the 16-row column reads).
    __shared__ __align__(16) _Float16 Xs[2][MB][136];      // x_t f16, dbuf
    __shared__ __align__(16) _Float16 Hs[MB][136];         // h f16
    __shared__ __align__(16) _Float16 XIs[MB][136];        // x_in f16
    __shared__ __align__(16) _Float16 HIs[MB][136];        // h_in f16

    // ---- register/AGPR-resident B-fragments (192 regs) ----
    f16x8 WHO[4][4], WXI[4][4], WHI[4][4];   // [kt][gate]
#pragma unroll
    for (int kt = 0; kt < 4; ++kt)
#pragma unroll
        for (int g = 0; g < 4; ++g) {
            const int col = 128 * g + 16 * w + l15;
            const int kb  = kt * 32 + l4 * 8;
            f16x8 va, vb, vc;
#pragma unroll
            for (int e = 0; e < 8; ++e) {
                va[e] = (_Float16)Wh_out[(size_t)(kb + e) * GG + col];
                vb[e] = (_Float16)Wx_in [(size_t)(kb + e) * GG + col];
                vc[e] = (_Float16)Wh_in [(size_t)(kb + e) * GG + col];
            }
            WHO[kt][g] = va; WXI[kt][g] = vb; WHI[kt][g] = vc;
        }

    // Wx_out -> LDS frags (each wave stages the 8 frags it will read)
#pragma unroll
    for (int kt = 0; kt < 2; ++kt)
#pragma unroll
        for (int g = 0; g < 4; ++g) {
            const int col = 128 * g + 16 * w + l15;
            const int kb  = kt * 32 + l4 * 8;
            f16x8 v;
#pragma unroll
            for (int e = 0; e < 8; ++e)
                v[e] = (_Float16)Wx_out[(size_t)(kb + e) * GG + col];
            *(f16x8*)&WXF[kt][8 * g + w][lane][0] = v;
        }
    // W_lin^T -> LDS frags (waves 0..3): B[k][col] = W_lin[col][k]
    if (w < 4)
#pragma unroll
        for (int kt = 0; kt < 4; ++kt) {
            const int col = 16 * w + l15;
            const int kb  = kt * 32 + l4 * 8;
            f16x8 v;
#pragma unroll
            for (int e = 0; e < 8; ++e)
                v[e] = (_Float16)W_lin[(size_t)col * HH + kb + e];
            *(f16x8*)&WLF[kt][w][lane][0] = v;
        }

    const float bo0 = b_out[16 * w + l15];
    const float bo1 = b_out[128 + 16 * w + l15];
    const float bo2 = b_out[256 + 16 * w + l15];
    const float bo3 = b_out[384 + 16 * w + l15];
    const float bi0 = b_in[16 * w + l15];
    const float bi1 = b_in[128 + 16 * w + l15];
    const float bi2 = b_in[256 + 16 * w + l15];
    const float bi3 = b_in[384 + 16 * w + l15];
    const float bl  = (w < 4) ? b_lin[16 * w + l15] : 0.f;

    // zero Hs (h0 = 0)
    for (int idx = tid; idx < MB * 136; idx += 512)
        ((_Float16*)Hs)[idx] = (_Float16)0.0f;
    // stage Xs[0] (t=0): 2 values/thread
    {
        const int r  = tid >> 5;
        const int i2 = (tid & 31) * 2;
        const float v0 = x[(size_t)(b0 + r) * II * SS + (size_t)i2 * SS];
        const float v1 = x[(size_t)(b0 + r) * II * SS + (size_t)(i2 + 1) * SS];
        f16x2 p; p.x = (_Float16)v0; p.y = (_Float16)v1;
        *(f16x2*)&Xs[0][r][i2] = p;
    }
    // thread-local state: batches l4*4+r, h-col 16w+l15
    f32x4 c_r  = {0.f, 0.f, 0.f, 0.f};
    f32x4 cn_r = {0.f, 0.f, 0.f, 0.f};
    float o_r[4];
    __syncthreads();

#pragma unroll 1
    for (int t = 0; t < SS; ++t) {
        const int cur = t & 1, nxt = cur ^ 1;

        // ======== phase A: outer gates [16 x 512] ========
        f32x4 a0 = {bo0, bo0, bo0, bo0};
        f32x4 a1 = {bo1, bo1, bo1, bo1};
        f32x4 a2 = {bo2, bo2, bo2, bo2};
        f32x4 a3 = {bo3, bo3, bo3, bo3};
#pragma unroll
        for (int kt = 0; kt < 2; ++kt) {
            const f16x8 xa = *(const f16x8*)&Xs[cur][l15][kt * 32 + l4 * 8];
            a0 = MFMA16(xa, *(const f16x8*)&WXF[kt][ 0 + w][lane][0], a0, 0, 0, 0);
            a1 = MFMA16(xa, *(const f16x8*)&WXF[kt][ 8 + w][lane][0], a1, 0, 0, 0);
            a2 = MFMA16(xa, *(const f16x8*)&WXF[kt][16 + w][lane][0], a2, 0, 0, 0);
            a3 = MFMA16(xa, *(const f16x8*)&WXF[kt][24 + w][lane][0], a3, 0, 0, 0);
        }
#pragma unroll
        for (int kt = 0; kt < 4; ++kt) {
            const f16x8 ha = *(const f16x8*)&Hs[l15][kt * 32 + l4 * 8];
            a0 = MFMA16(ha, WHO[kt][0], a0, 0, 0, 0);
            a1 = MFMA16(ha, WHO[kt][1], a1, 0, 0, 0);
            a2 = MFMA16(ha, WHO[kt][2], a2, 0, 0, 0);
            a3 = MFMA16(ha, WHO[kt][3], a3, 0, 0, 0);
        }
        // acts + wave-local elementwise (batch = l4*4+r, h-col = 16w+l15)
#pragma unroll
        for (int r = 0; r < 4; ++r) {
            const float iv = sigm(a0[r]);
            const float fv = sigm(a1[r]);
            o_r[r]         = sigm(a2[r]);
            const float gv = tanh_f(a3[r]);
            const int row = l4 * 4 + r, hc = 16 * w + l15;
            XIs[row][hc] = (_Float16)(iv * gv);
            HIs[row][hc] = (_Float16)(fv * c_r[r]);
        }
        __syncthreads();   // S1

        // ======== phase C: inner gates (+ x(t+1) gather on waves 4..7) ========
        float xg0, xg1, xg2, xg3;
        const bool doG = (w >= 4) && (t + 1 < SS);
        if (doG) {
            const int v  = tid - 256;
            const int r  = v >> 4;
            const int ib = (v & 15) * 4;
            const float* px = x + (size_t)(b0 + r) * II * SS + (size_t)ib * SS + (t + 1);
            xg0 = px[0]; xg1 = px[SS]; xg2 = px[2 * SS]; xg3 = px[3 * SS];
        }
        f32x4 c0 = {bi0, bi0, bi0, bi0};
        f32x4 c1 = {bi1, bi1, bi1, bi1};
        f32x4 c2 = {bi2, bi2, bi2, bi2};
        f32x4 c3 = {bi3, bi3, bi3, bi3};
#pragma unroll
        for (int kt = 0; kt < 4; ++kt) {
            const f16x8 xia = *(const f16x8*)&XIs[l15][kt * 32 + l4 * 8];
            c0 = MFMA16(xia, WXI[kt][0], c0, 0, 0, 0);
            c1 = MFMA16(xia, WXI[kt][1], c1, 0, 0, 0);
            c2 = MFMA16(xia, WXI[kt][2], c2, 0, 0, 0);
            c3 = MFMA16(xia, WXI[kt][3], c3, 0, 0, 0);
        }
#pragma unroll
        for (int kt = 0; kt < 4; ++kt) {
            const f16x8 hia = *(const f16x8*)&HIs[l15][kt * 32 + l4 * 8];
            c0 = MFMA16(hia, WHI[kt][0], c0, 0, 0, 0);
            c1 = MFMA16(hia, WHI[kt][1], c1, 0, 0, 0);
            c2 = MFMA16(hia, WHI[kt][2], c2, 0, 0, 0);
            c3 = MFMA16(hia, WHI[kt][3], c3, 0, 0, 0);
        }
        // acts + state update, fully wave-local
#pragma unroll
        for (int r = 0; r < 4; ++r) {
            const float ii = sigm(c0[r]);
            const float fi = sigm(c1[r]);
            const float oi = sigm(c2[r]);
            const float gi = tanh_f(c3[r]);
            const float cnn  = fi * cn_r[r] + ii * gi;
            const float cnew = oi * tanh_f(cnn);
            const float hnew = o_r[r] * tanh_f(cnew);
            cn_r[r] = cnn;
            c_r[r]  = cnew;
            Hs[l4 * 4 + r][16 * w + l15] = (_Float16)hnew;
        }
        if (doG) {   // write x(t+1) into the other X buffer
            const int v  = tid - 256;
            const int r  = v >> 4;
            const int ib = (v & 15) * 4;
            f16x2 p0; p0.x = (_Float16)xg0; p0.y = (_Float16)xg1;
            f16x2 p1; p1.x = (_Float16)xg2; p1.y = (_Float16)xg3;
            *(f16x2*)&Xs[nxt][r][ib]     = p0;
            *(f16x2*)&Xs[nxt][r][ib + 2] = p1;
        }
        __syncthreads();   // S2

        // ======== projection (waves 0..3) — overlaps next A on waves 4..7 ====
        if (w < 4) {
            f32x4 p = {bl, bl, bl, bl};
#pragma unroll
            for (int kt = 0; kt < 4; ++kt) {
                const f16x8 hA = *(const f16x8*)&Hs[l15][kt * 32 + l4 * 8];
                p = MFMA16(hA, *(const f16x8*)&WLF[kt][w][lane][0], p, 0, 0, 0);
            }
#pragma unroll
            for (int r = 0; r < 4; ++r)
                out[(size_t)(b0 + l4 * 4 + r) * SS * OO + (size_t)t * OO
                    + 16 * w + l15] = p[r];
        }
    }
}

extern "C" void kernel_launch(void* const* d_in, const int* in_sizes, int n_in,
                              void* d_out, int out_size, void* d_ws, size_t ws_size,
                              hipStream_t stream) {
    (void)in_sizes; (void)n_in; (void)d_ws; (void)ws_size; (void)out_size;
    const float* x      = (const float*)d_in[0];
    const float* Wx_out = (const float*)d_in[1];
    const float* Wh_out = (const float*)d_in[2];
    const float* b_out  = (const float*)d_in[3];
    const float* Wx_in  = (const float*)d_in[4];
    const float* Wh_in  = (const float*)d_in[5];
    const float* b_in   = (const float*)d_in[6];
    const float* W_lin  = (const float*)d_in[7];
    const float* b_lin  = (const float*)d_in[8];
    float* out = (float*)d_out;

    nlstm_mfma<<<dim3(NBLK), dim3(512), 0, stream>>>(
        x, Wx_out, Wh_out, b_out, Wx_in, Wh_in, b_in, W_lin, b_lin, out);
}

// Round 6
// 4044.093 us; speedup vs baseline: 2.7962x; 1.8027x over previous
//
#include <hip/hip_runtime.h>
#include <hip/hip_fp16.h>

#define BB 128
#define II 64
#define SS 2048
#define HH 128
#define GG 512   // 4*H
#define OO 64
#define TT 32    // x time-tile width (fallback kernel)
#define TCH 128  // precompute t-chunk
#define XPBYTES ((size_t)BB * SS * GG * 2)

typedef _Float16 f16x2 __attribute__((ext_vector_type(2)));
union F4H { float4 f4; f16x2 h[4]; };

__device__ __forceinline__ f16x2 pack2(float a, float b) {
    f16x2 r; r.x = (_Float16)a; r.y = (_Float16)b; return r;
}

__device__ __forceinline__ float dot2(f16x2 w, f16x2 v, float c) {
#if __has_builtin(__builtin_amdgcn_fdot2)
    return __builtin_amdgcn_fdot2(w, v, c, false);
#else
    return fmaf((float)w.x, (float)v.x, fmaf((float)w.y, (float)v.y, c));
#endif
}

__device__ __forceinline__ float sigm(float v) {
    return __builtin_amdgcn_rcpf(1.0f + __expf(-v));
}
// original tanh (fallback kernel keeps R1 bit-exact behavior)
__device__ __forceinline__ float tanh_f(float v) {
    float a = fabsf(v);
    float e = __expf(-2.0f * a);
    float r = (1.0f - e) * __builtin_amdgcn_rcpf(1.0f + e);
    return v < 0.0f ? -r : r;
}
// branch-free tanh = 2*sigm(2v)-1 (safe at +/-inf: exp->{0,inf} -> {1,-1})
__device__ __forceinline__ float tanh_c(float v) {
    return fmaf(2.0f, __builtin_amdgcn_rcpf(1.0f + __expf(-2.0f * v)), -1.0f);
}

// ============================================================================
// XP precompute: XP[b][t][j] = sum_i x[b,i,t] * Wx_out[i,j], stored f16.
// Grid (16,128): block = (t-chunk, batch). 17 GFLOP total ~55us VALU.
// ============================================================================
__global__ void __launch_bounds__(512)
xp_gemm(const float* __restrict__ x, const float* __restrict__ Wx_out,
        _Float16* __restrict__ xp)
{
    const int tc = blockIdx.x;          // 0..15
    const int b  = blockIdx.y;          // 0..127
    const int j  = threadIdx.x;         // gate column 0..511
    const int t0 = tc * TCH;

    // x pairs, [tt][c]: stride 36 f16x2 = 144 B (16B-aligned rows)
    __shared__ __align__(16) f16x2 x2s[TCH][36];

    // register weights: w2[c] = (Wx_out[2c][j], Wx_out[2c+1][j])
    f16x2 w2[32];
#pragma unroll
    for (int c = 0; c < 32; ++c)
        w2[c] = pack2(Wx_out[(2 * c) * GG + j], Wx_out[(2 * c + 1) * GG + j]);

    // stage x[b][:, t0:t0+128]: 64 rows x 32 float4, 4 per thread
    const float* xrow = x + (size_t)b * II * SS;
    const int r = j >> 3;               // row 0..63
#pragma unroll
    for (int rep = 0; rep < 4; ++rep) {
        const int u = (j & 7) + 8 * rep;            // 0..31
        const float4 v = *(const float4*)(xrow + (size_t)r * SS + t0 + 4 * u);
        const int c = r >> 1, half = r & 1;
        ((_Float16*)&x2s[4 * u + 0][c])[half] = (_Float16)v.x;
        ((_Float16*)&x2s[4 * u + 1][c])[half] = (_Float16)v.y;
        ((_Float16*)&x2s[4 * u + 2][c])[half] = (_Float16)v.z;
        ((_Float16*)&x2s[4 * u + 3][c])[half] = (_Float16)v.w;
    }
    __syncthreads();

    _Float16* xpo = xp + ((size_t)b * SS + t0) * GG + j;
#pragma unroll 4
    for (int tt = 0; tt < TCH; ++tt) {
        const float4* xr4 = (const float4*)&x2s[tt][0];   // 8 broadcast b128
        float a0 = 0.f, a1 = 0.f;
#pragma unroll
        for (int q = 0; q < 8; ++q) {
            F4H u; u.f4 = xr4[q];
            a0 = dot2(w2[4 * q + 0], u.h[0], a0);
            a1 = dot2(w2[4 * q + 1], u.h[1], a1);
            a0 = dot2(w2[4 * q + 2], u.h[2], a0);
            a1 = dot2(w2[4 * q + 3], u.h[3], a1);
        }
        xpo[(size_t)tt * GG] = (_Float16)(a0 + a1);
    }
}

// ============================================================================
// Scan with precomputed XP: R1 structure minus all x staging. Phase A's x-part
// is one prefetched coalesced f16 load (issued ~2500 cyc before use).
// ============================================================================
__global__ void __launch_bounds__(512)
nlstm_scan_xp(
    const _Float16* __restrict__ xp,
    const float* __restrict__ Wh_out, const float* __restrict__ b_out,
    const float* __restrict__ Wx_in, const float* __restrict__ Wh_in,
    const float* __restrict__ b_in,
    const float* __restrict__ W_lin, const float* __restrict__ b_lin,
    float* __restrict__ out)
{
    const int b = blockIdx.x;
    const int j = threadIdx.x;

    __shared__ __align__(16) float4 wlf[16 * 66];          // W_lin fp16, 16.5 KB
    __shared__ __align__(16) f16x2 hb[HH / 2];
    __shared__ __align__(16) f16x2 xib[HH / 2];
    __shared__ __align__(16) f16x2 hib[HH / 2];
    __shared__ float cb[HH];
    __shared__ float cnb[HH];
    __shared__ float actO[GG];
    __shared__ float actI[GG];

    // register-resident fp16 weights (column j) : 192 regs (AGPR-backed)
    f16x2 who[HH / 2], wxi[HH / 2], whi[HH / 2];
#pragma unroll
    for (int m = 0; m < HH / 2; ++m)
        who[m] = pack2(Wh_out[(2 * m) * GG + j], Wh_out[(2 * m + 1) * GG + j]);
#pragma unroll
    for (int m = 0; m < HH / 2; ++m)
        wxi[m] = pack2(Wx_in[(2 * m) * GG + j], Wx_in[(2 * m + 1) * GG + j]);
#pragma unroll
    for (int m = 0; m < HH / 2; ++m)
        whi[m] = pack2(Wh_in[(2 * m) * GG + j], Wh_in[(2 * m + 1) * GG + j]);

    const float bo = b_out[j];
    const float bi = b_in[j];
    const int   pn = j >> 3;
    const int   ps = j & 7;
    const float bl = b_lin[pn];

    // W_lin -> LDS fp16 (1024 chunks, 2 per thread)
#pragma unroll
    for (int r = 0; r < 2; ++r) {
        const int m = r * 512 + j;
        const int c = m >> 6, n = m & 63;
        F4H u;
#pragma unroll
        for (int q = 0; q < 4; ++q)
            u.h[q] = pack2(W_lin[n * HH + 8 * c + 2 * q],
                           W_lin[n * HH + 8 * c + 2 * q + 1]);
        wlf[c * 66 + n] = u.f4;
    }

    if (j < HH / 2) hb[j] = pack2(0.f, 0.f);
    if (j < HH) { cb[j] = 0.f; cnb[j] = 0.f; }
    __syncthreads();

    const _Float16* xpr = xp + (size_t)b * SS * GG + j;
    float* orow = out + (size_t)b * SS * OO;
    const float4* hb4 = (const float4*)hb;
    const float4* xi4 = (const float4*)xib;
    const float4* hi4 = (const float4*)hib;

    _Float16 xpc = xpr[0];

#pragma unroll 1
    for (int t = 0; t < SS; ++t) {
        // ---- phase A: outer gates = XP + h@Wh_out + b ----
        float a0 = bo + (float)xpc, a1 = 0.f, a2 = 0.f, a3 = 0.f;
#pragma unroll
        for (int c = 0; c < 16; ++c) {
            F4H hu; hu.f4 = hb4[c];
            a0 = dot2(who[4 * c + 0], hu.h[0], a0);
            a1 = dot2(who[4 * c + 1], hu.h[1], a1);
            a2 = dot2(who[4 * c + 2], hu.h[2], a2);
            a3 = dot2(who[4 * c + 3], hu.h[3], a3);
        }
        // prefetch next step's XP (independent; lands during C/D phases)
        const _Float16 xpn = xpr[(size_t)(((t + 1) & (SS - 1))) * GG];
        {
            const float acc = (a0 + a1) + (a2 + a3);
            actO[j] = (j < 384) ? sigm(acc) : tanh_c(acc);
        }
        __syncthreads();   // B2

        // ---- phase B: inner-LSTM inputs (spread across all waves) ----
        if ((j & 7) == 0) {            // xib, m = j>>3 in 0..63
            const int m = j >> 3;
            xib[m] = pack2(actO[2 * m] * actO[384 + 2 * m],
                           actO[2 * m + 1] * actO[384 + 2 * m + 1]);
        } else if ((j & 7) == 4) {     // hib
            const int m = j >> 3;
            hib[m] = pack2(actO[HH + 2 * m] * cb[2 * m],
                           actO[HH + 2 * m + 1] * cb[2 * m + 1]);
        }
        __syncthreads();   // B3

        // ---- phase C: inner gates ----
        float c0 = bi, c1 = 0.f, c2 = 0.f, c3 = 0.f;
#pragma unroll
        for (int c = 0; c < 16; ++c) {
            F4H xu; xu.f4 = xi4[c];
            c0 = dot2(wxi[4 * c + 0], xu.h[0], c0);
            c1 = dot2(wxi[4 * c + 1], xu.h[1], c1);
            c2 = dot2(wxi[4 * c + 2], xu.h[2], c2);
            c3 = dot2(wxi[4 * c + 3], xu.h[3], c3);
        }
#pragma unroll
        for (int c = 0; c < 16; ++c) {
            F4H hu; hu.f4 = hi4[c];
            c0 = dot2(whi[4 * c + 0], hu.h[0], c0);
            c1 = dot2(whi[4 * c + 1], hu.h[1], c1);
            c2 = dot2(whi[4 * c + 2], hu.h[2], c2);
            c3 = dot2(whi[4 * c + 3], hu.h[3], c3);
        }
        {
            const float acc2 = (c0 + c1) + (c2 + c3);
            actI[j] = (j < 384) ? sigm(acc2) : tanh_c(acc2);
        }
        __syncthreads();   // B4

        // ---- phase D: state update (spread: threads 0,4,8,..,508) ----
        if ((j & 3) == 0) {
            const int m = j >> 2;
            const float cn_new = actI[HH + m] * cnb[m] + actI[m] * actI[384 + m];
            const float c_new  = actI[2 * HH + m] * tanh_c(cn_new);
            const float h_new  = actO[2 * HH + m] * tanh_c(c_new);
            cnb[m] = cn_new;
            cb[m]  = c_new;
            ((_Float16*)hb)[m] = (_Float16)h_new;
        }
        __syncthreads();   // B5

        // ---- phase E: fused projection ----
        float p = 0.f;
#pragma unroll
        for (int q = 0; q < 2; ++q) {
            const int c = 2 * ps + q;
            F4H hu; hu.f4 = hb4[c];
            F4H wu; wu.f4 = wlf[c * 66 + pn];
            p = dot2(wu.h[0], hu.h[0], p);
            p = dot2(wu.h[1], hu.h[1], p);
            p = dot2(wu.h[2], hu.h[2], p);
            p = dot2(wu.h[3], hu.h[3], p);
        }
        p += __shfl_down(p, 4, 8);
        p += __shfl_down(p, 2, 8);
        p += __shfl_down(p, 1, 8);
        if (ps == 0) orow[t * OO + pn] = p + bl;

        xpc = xpn;
    }
}

// ============================================================================
// FALLBACK: exact R1 kernel (measured 4364 us) for when ws is too small.
// ============================================================================
__global__ void
__attribute__((amdgpu_flat_work_group_size(512, 512)))
__attribute__((amdgpu_waves_per_eu(2, 2)))
nlstm_scan(
    const float* __restrict__ x,
    const float* __restrict__ Wx_out, const float* __restrict__ Wh_out,
    const float* __restrict__ b_out,
    const float* __restrict__ Wx_in, const float* __restrict__ Wh_in,
    const float* __restrict__ b_in,
    const float* __restrict__ W_lin, const float* __restrict__ b_lin,
    float* __restrict__ out)
{
    const int b = blockIdx.x;
    const int j = threadIdx.x;

    __shared__ __align__(16) float4 wxf[8 * 512];
    __shared__ __align__(16) float4 wlf[16 * 66];
    __shared__ float xt[2][II][TT + 1];
    __shared__ __align__(16) f16x2 xb[2][II / 2];
    __shared__ __align__(16) f16x2 hb[HH / 2];
    __shared__ __align__(16) f16x2 xib[HH / 2];
    __shared__ __align__(16) f16x2 hib[HH / 2];
    __shared__ float cb[HH];
    __shared__ float cnb[HH];
    __shared__ float actO[GG];
    __shared__ float actI[GG];

    f16x2 who[HH / 2], wxi[HH / 2], whi[HH / 2];
#pragma unroll
    for (int m = 0; m < HH / 2; ++m)
        who[m] = pack2(Wh_out[(2 * m) * GG + j], Wh_out[(2 * m + 1) * GG + j]);
#pragma unroll
    for (int m = 0; m < HH / 2; ++m)
        wxi[m] = pack2(Wx_in[(2 * m) * GG + j], Wx_in[(2 * m + 1) * GG + j]);
#pragma unroll
    for (int m = 0; m < HH / 2; ++m)
        whi[m] = pack2(Wh_in[(2 * m) * GG + j], Wh_in[(2 * m + 1) * GG + j]);

    const float bo = b_out[j];
    const float bi = b_in[j];
    const int   pn = j >> 3;
    const int   ps = j & 7;
    const float bl = b_lin[pn];

#pragma unroll
    for (int c = 0; c < 8; ++c) {
        F4H u;
#pragma unroll
        for (int q = 0; q < 4; ++q)
            u.h[q] = pack2(Wx_out[(8 * c + 2 * q) * GG + j],
                           Wx_out[(8 * c + 2 * q + 1) * GG + j]);
        wxf[c * 512 + j] = u.f4;
    }
#pragma unroll
    for (int r = 0; r < 2; ++r) {
        const int m = r * 512 + j;
        const int c = m >> 6, n = m & 63;
        F4H u;
#pragma unroll
        for (int q = 0; q < 4; ++q)
            u.h[q] = pack2(W_lin[n * HH + 8 * c + 2 * q],
                           W_lin[n * HH + 8 * c + 2 * q + 1]);
        wlf[c * 66 + n] = u.f4;
    }

    const float* xrow = x + (size_t)b * II * SS;
    float* orow = out + (size_t)b * SS * OO;

    {
        const int row = j >> 3, tc = j & 7;
        const float4 v = *(const float4*)(xrow + (size_t)row * SS + 4 * tc);
        float* dst = &xt[0][row][4 * tc];
        dst[0] = v.x; dst[1] = v.y; dst[2] = v.z; dst[3] = v.w;
    }
    if (j < HH / 2) hb[j] = pack2(0.f, 0.f);
    if (j < HH) { cb[j] = 0.f; cnb[j] = 0.f; }
    if (j >= 256 && j < 256 + 32) {
        const int m = j - 256;
        xb[0][m] = pack2(xrow[(2 * m) * SS], xrow[(2 * m + 1) * SS]);
    }
    __syncthreads();

    const float4* hb4 = (const float4*)hb;
    const float4* xi4 = (const float4*)xib;
    const float4* hi4 = (const float4*)hib;

#pragma unroll 1
    for (int t = 0; t < SS; ++t) {
        const float4* xcur = (const float4*)xb[t & 1];
        float a0 = bo, a1 = 0.f, a2 = 0.f, a3 = 0.f;
#pragma unroll
        for (int c = 0; c < 8; ++c) {
            F4H xu; xu.f4 = xcur[c];
            F4H wu; wu.f4 = wxf[c * 512 + j];
            a0 = dot2(wu.h[0], xu.h[0], a0);
            a1 = dot2(wu.h[1], xu.h[1], a1);
            a2 = dot2(wu.h[2], xu.h[2], a2);
            a3 = dot2(wu.h[3], xu.h[3], a3);
        }
#pragma unroll
        for (int c = 0; c < 16; ++c) {
            F4H hu; hu.f4 = hb4[c];
            a0 = dot2(who[4 * c + 0], hu.h[0], a0);
            a1 = dot2(who[4 * c + 1], hu.h[1], a1);
            a2 = dot2(who[4 * c + 2], hu.h[2], a2);
            a3 = dot2(who[4 * c + 3], hu.h[3], a3);
        }
        {
            const float acc = (a0 + a1) + (a2 + a3);
            actO[j] = (j < 384) ? sigm(acc) : tanh_f(acc);
        }
        __syncthreads();

        if (j < II) {
            xib[j] = pack2(actO[2 * j] * actO[384 + 2 * j],
                           actO[2 * j + 1] * actO[384 + 2 * j + 1]);
        } else if (j < II + HH / 2) {
            const int m = j - II;
            hib[m] = pack2(actO[HH + 2 * m] * cb[2 * m],
                           actO[HH + 2 * m + 1] * cb[2 * m + 1]);
        }
        __syncthreads();

        float c0 = bi, c1 = 0.f, c2 = 0.f, c3 = 0.f;
#pragma unroll
        for (int c = 0; c < 16; ++c) {
            F4H xu; xu.f4 = xi4[c];
            c0 = dot2(wxi[4 * c + 0], xu.h[0], c0);
            c1 = dot2(wxi[4 * c + 1], xu.h[1], c1);
            c2 = dot2(wxi[4 * c + 2], xu.h[2], c2);
            c3 = dot2(wxi[4 * c + 3], xu.h[3], c3);
        }
#pragma unroll
        for (int c = 0; c < 16; ++c) {
            F4H hu; hu.f4 = hi4[c];
            c0 = dot2(whi[4 * c + 0], hu.h[0], c0);
            c1 = dot2(whi[4 * c + 1], hu.h[1], c1);
            c2 = dot2(whi[4 * c + 2], hu.h[2], c2);
            c3 = dot2(whi[4 * c + 3], hu.h[3], c3);
        }
        {
            const float acc2 = (c0 + c1) + (c2 + c3);
            actI[j] = (j < 384) ? sigm(acc2) : tanh_f(acc2);
        }
        __syncthreads();

        const bool doTile = ((t & 31) == 30) && (t + 2 < SS);
        float4 xld; int Tn = 0;
        if (doTile) {
            Tn = (t + 2) >> 5;
            const int row = j >> 3, tc = j & 7;
            xld = *(const float4*)(xrow + (size_t)row * SS + TT * Tn + 4 * tc);
        }
        if (j < HH) {
            const float cn_new = actI[HH + j] * cnb[j] + actI[j] * actI[384 + j];
            const float c_new  = actI[2 * HH + j] * tanh_f(cn_new);
            const float h_new  = actO[2 * HH + j] * tanh_f(c_new);
            cnb[j] = cn_new;
            cb[j]  = c_new;
            ((_Float16*)hb)[j] = (_Float16)h_new;
        } else if (j < HH + 32) {
            const int m = j - HH;
            const int tn = t + 1;
            const int tbn = (tn >> 5) & 1, ttn = tn & 31;
            xb[tn & 1][m] = pack2(xt[tbn][2 * m][ttn],
                                  xt[tbn][2 * m + 1][ttn]);
        }
        if (doTile) {
            const int row = j >> 3, tc = j & 7;
            float* dst = &xt[Tn & 1][row][4 * tc];
            dst[0] = xld.x; dst[1] = xld.y; dst[2] = xld.z; dst[3] = xld.w;
        }
        __syncthreads();

        float p = 0.f;
#pragma unroll
        for (int q = 0; q < 2; ++q) {
            const int c = 2 * ps + q;
            F4H hu; hu.f4 = hb4[c];
            F4H wu; wu.f4 = wlf[c * 66 + pn];
            p = dot2(wu.h[0], hu.h[0], p);
            p = dot2(wu.h[1], hu.h[1], p);
            p = dot2(wu.h[2], hu.h[2], p);
            p = dot2(wu.h[3], hu.h[3], p);
        }
        p += __shfl_down(p, 4, 8);
        p += __shfl_down(p, 2, 8);
        p += __shfl_down(p, 1, 8);
        if (ps == 0) orow[t * OO + pn] = p + bl;
    }
}

extern "C" void kernel_launch(void* const* d_in, const int* in_sizes, int n_in,
                              void* d_out, int out_size, void* d_ws, size_t ws_size,
                              hipStream_t stream) {
    (void)in_sizes; (void)n_in; (void)out_size;
    const float* x      = (const float*)d_in[0];
    const float* Wx_out = (const float*)d_in[1];
    const float* Wh_out = (const float*)d_in[2];
    const float* b_out  = (const float*)d_in[3];
    const float* Wx_in  = (const float*)d_in[4];
    const float* Wh_in  = (const float*)d_in[5];
    const float* b_in   = (const float*)d_in[6];
    const float* W_lin  = (const float*)d_in[7];
    const float* b_lin  = (const float*)d_in[8];
    float* out = (float*)d_out;

    if (d_ws != nullptr && ws_size >= XPBYTES) {
        _Float16* xpw = (_Float16*)d_ws;
        xp_gemm<<<dim3(16, BB), dim3(512), 0, stream>>>(x, Wx_out, xpw);
        nlstm_scan_xp<<<dim3(BB), dim3(512), 0, stream>>>(
            xpw, Wh_out, b_out, Wx_in, Wh_in, b_in, W_lin, b_lin, out);
    } else {
        nlstm_scan<<<dim3(BB), dim3(512), 0, stream>>>(
            x, Wx_out, Wh_out, b_out, Wx_in, Wh_in, b_in, W_lin, b_lin, out);
    }
}

// Round 7
// 3708.004 us; speedup vs baseline: 3.0497x; 1.0906x over previous
//
#include <hip/hip_runtime.h>
#include <hip/hip_fp16.h>

#define BB 128
#define II 64
#define SS 2048
#define HH 128
#define GG 512   // 4*H
#define OO 64
#define TT 32    // x time-tile width (fallback kernel)
#define TCH 128  // precompute t-chunk
#define XPBYTES ((size_t)BB * SS * GG * 2)

typedef _Float16 f16x2 __attribute__((ext_vector_type(2)));
union F4H { float4 f4; f16x2 h[4]; };

__device__ __forceinline__ f16x2 pack2(float a, float b) {
    f16x2 r; r.x = (_Float16)a; r.y = (_Float16)b; return r;
}

__device__ __forceinline__ float dot2(f16x2 w, f16x2 v, float c) {
#if __has_builtin(__builtin_amdgcn_fdot2)
    return __builtin_amdgcn_fdot2(w, v, c, false);
#else
    return fmaf((float)w.x, (float)v.x, fmaf((float)w.y, (float)v.y, c));
#endif
}

__device__ __forceinline__ float sigm(float v) {
    return __builtin_amdgcn_rcpf(1.0f + __expf(-v));
}
// original tanh (fallback kernel keeps R1 bit-exact behavior)
__device__ __forceinline__ float tanh_f(float v) {
    float a = fabsf(v);
    float e = __expf(-2.0f * a);
    float r = (1.0f - e) * __builtin_amdgcn_rcpf(1.0f + e);
    return v < 0.0f ? -r : r;
}
// branch-free tanh = 2*sigm(2v)-1 (safe at +/-inf)
__device__ __forceinline__ float tanh_c(float v) {
    return fmaf(2.0f, __builtin_amdgcn_rcpf(1.0f + __expf(-2.0f * v)), -1.0f);
}

// ============================================================================
// XP precompute: XP[b][t][j] = sum_i x[b,i,t] * Wx_out[i,j], stored f16.
// ============================================================================
__global__ void __launch_bounds__(512)
xp_gemm(const float* __restrict__ x, const float* __restrict__ Wx_out,
        _Float16* __restrict__ xp)
{
    const int tc = blockIdx.x;          // 0..15
    const int b  = blockIdx.y;          // 0..127
    const int j  = threadIdx.x;         // gate column 0..511
    const int t0 = tc * TCH;

    __shared__ __align__(16) f16x2 x2s[TCH][36];

    f16x2 w2[32];
#pragma unroll
    for (int c = 0; c < 32; ++c)
        w2[c] = pack2(Wx_out[(2 * c) * GG + j], Wx_out[(2 * c + 1) * GG + j]);

    const float* xrow = x + (size_t)b * II * SS;
    const int r = j >> 3;
#pragma unroll
    for (int rep = 0; rep < 4; ++rep) {
        const int u = (j & 7) + 8 * rep;
        const float4 v = *(const float4*)(xrow + (size_t)r * SS + t0 + 4 * u);
        const int c = r >> 1, half = r & 1;
        ((_Float16*)&x2s[4 * u + 0][c])[half] = (_Float16)v.x;
        ((_Float16*)&x2s[4 * u + 1][c])[half] = (_Float16)v.y;
        ((_Float16*)&x2s[4 * u + 2][c])[half] = (_Float16)v.z;
        ((_Float16*)&x2s[4 * u + 3][c])[half] = (_Float16)v.w;
    }
    __syncthreads();

    _Float16* xpo = xp + ((size_t)b * SS + t0) * GG + j;
#pragma unroll 4
    for (int tt = 0; tt < TCH; ++tt) {
        const float4* xr4 = (const float4*)&x2s[tt][0];
        float a0 = 0.f, a1 = 0.f;
#pragma unroll
        for (int q = 0; q < 8; ++q) {
            F4H u; u.f4 = xr4[q];
            a0 = dot2(w2[4 * q + 0], u.h[0], a0);
            a1 = dot2(w2[4 * q + 1], u.h[1], a1);
            a0 = dot2(w2[4 * q + 2], u.h[2], a0);
            a1 = dot2(w2[4 * q + 3], u.h[3], a1);
        }
        xpo[(size_t)tt * GG] = (_Float16)(a0 + a1);
    }
}

// ============================================================================
// Scan, quad-gate layout: thread j owns gate g=j&3 of h-column m=j>>2
// (col = g*128 + m). A lane-quad holds (i,f,o,g) of one column, so the
// elementwise phases run as quad-local shuffles + register math:
//   - x_in = i*g, h_in = f*c  : 2 shuffles in phase-A tail  (old phase B gone)
//   - full state update (cn,c,h): shuffles in phase-C tail  (old phase D gone)
// c lives in lane2, cn in lane1 of each quad; actO/actI/cb/cnb LDS deleted.
// 2 barriers/step (was 4): removes 2 LDS round-trips + 2 barrier skews from
// the serial chain that R6 counters showed as ~2550 stall cyc/step.
// ============================================================================
__global__ void __launch_bounds__(512)
nlstm_scan_xp(
    const _Float16* __restrict__ xp,
    const float* __restrict__ Wh_out, const float* __restrict__ b_out,
    const float* __restrict__ Wx_in, const float* __restrict__ Wh_in,
    const float* __restrict__ b_in,
    const float* __restrict__ W_lin, const float* __restrict__ b_lin,
    float* __restrict__ out)
{
    const int b = blockIdx.x;
    const int j = threadIdx.x;
    const int g = j & 3;          // gate lane within quad: 0=i 1=f 2=o 3=g
    const int m = j >> 2;         // h-column 0..127
    const int col = g * 128 + m;  // gate column in canonical layout

    __shared__ __align__(16) float4 wlf[16 * 66];      // W_lin fp16, 16.5 KB
    __shared__ __align__(16) _Float16 hb[HH];          // h fp16
    __shared__ __align__(16) _Float16 xib[HH];         // x_in fp16
    __shared__ __align__(16) _Float16 hib[HH];         // h_in fp16

    // register-resident fp16 weights (column col) : 192 regs (AGPR-backed)
    f16x2 who[HH / 2], wxi[HH / 2], whi[HH / 2];
#pragma unroll
    for (int q = 0; q < HH / 2; ++q)
        who[q] = pack2(Wh_out[(2 * q) * GG + col], Wh_out[(2 * q + 1) * GG + col]);
#pragma unroll
    for (int q = 0; q < HH / 2; ++q)
        wxi[q] = pack2(Wx_in[(2 * q) * GG + col], Wx_in[(2 * q + 1) * GG + col]);
#pragma unroll
    for (int q = 0; q < HH / 2; ++q)
        whi[q] = pack2(Wh_in[(2 * q) * GG + col], Wh_in[(2 * q + 1) * GG + col]);

    const float bo = b_out[col];
    const float bi = b_in[col];
    // branch-free activation: gate<3 -> sigm(x); gate3 -> tanh(x)=2*sigm(2x)-1
    const float kk = (g == 3) ? 2.0f : 1.0f;
    const float aa = (g == 3) ? 2.0f : 1.0f;
    const float cc = (g == 3) ? -1.0f : 0.0f;

    const int   pn = j >> 3;
    const int   ps = j & 7;
    const float bl = b_lin[pn];

    // W_lin -> LDS fp16 (1024 chunks, 2 per thread)
#pragma unroll
    for (int r = 0; r < 2; ++r) {
        const int mm = r * 512 + j;
        const int c = mm >> 6, n = mm & 63;
        F4H u;
#pragma unroll
        for (int q = 0; q < 4; ++q)
            u.h[q] = pack2(W_lin[n * HH + 8 * c + 2 * q],
                           W_lin[n * HH + 8 * c + 2 * q + 1]);
        wlf[c * 66 + n] = u.f4;
    }

    if (j < HH) { hb[j] = (_Float16)0.f; xib[j] = (_Float16)0.f; hib[j] = (_Float16)0.f; }
    float c_reg = 0.f;    // meaningful at lane g==2
    float cn_reg = 0.f;   // meaningful at lane g==1
    float o_r = 0.f;      // outer o, meaningful at lane g==2
    __syncthreads();

    const _Float16* xpr = xp + (size_t)b * SS * GG + col;
    float* orow = out + (size_t)b * SS * OO;
    const float4* hb4 = (const float4*)hb;   // 16 chunks
    const float4* xi4 = (const float4*)xib;  // 8 chunks
    const float4* hi4 = (const float4*)hib;  // 8 chunks

    _Float16 xpc = xpr[0];

#pragma unroll 1
    for (int t = 0; t < SS; ++t) {
        // ---- phase A: outer gate for col = XP + h@Wh_out + b ----
        float a0 = bo + (float)xpc, a1 = 0.f, a2 = 0.f, a3 = 0.f;
#pragma unroll
        for (int c = 0; c < 16; ++c) {
            F4H hu; hu.f4 = hb4[c];
            a0 = dot2(who[4 * c + 0], hu.h[0], a0);
            a1 = dot2(who[4 * c + 1], hu.h[1], a1);
            a2 = dot2(who[4 * c + 2], hu.h[2], a2);
            a3 = dot2(who[4 * c + 3], hu.h[3], a3);
        }
        // prefetch next step's XP (independent; lands during phase C)
        const _Float16 xpn = xpr[(size_t)((t + 1) & (SS - 1)) * GG];
        const float accA = (a0 + a1) + (a2 + a3);
        const float v = fmaf(aa, sigm(kk * accA), cc);   // i/f/o/g by lane
        o_r = v;                                          // lane2 keeps o
        // quad tail: x_in = i*g (lane0), h_in = f*c_prev (lane1)
        {
            const float vg = __shfl_xor(v, 3);        // lane0 <- lane3 (g-val)
            const float cq = __shfl_xor(c_reg, 3);    // lane1 <- lane2 (c)
            if (g == 0)      xib[m] = (_Float16)(v * vg);
            else if (g == 1) hib[m] = (_Float16)(v * cq);
        }
        __syncthreads();   // S1

        // ---- phase C: inner gate for col ----
        float c0 = bi, c1 = 0.f, c2 = 0.f, c3 = 0.f;
#pragma unroll
        for (int c = 0; c < 8; ++c) {
            F4H xu; xu.f4 = xi4[c];
            c0 = dot2(wxi[8 * c + 0], xu.h[0], c0);
            c1 = dot2(wxi[8 * c + 1], xu.h[1], c1);
            c2 = dot2(wxi[8 * c + 2], xu.h[2], c2);
            c3 = dot2(wxi[8 * c + 3], xu.h[3], c3);
            F4H xu2; xu2.f4 = xi4[c];  // same chunk, regs 4..7
            c0 = dot2(wxi[8 * c + 4], xu2.h[0], c0);
            c1 = dot2(wxi[8 * c + 5], xu2.h[1], c1);
            c2 = dot2(wxi[8 * c + 6], xu2.h[2], c2);
            c3 = dot2(wxi[8 * c + 7], xu2.h[3], c3);
        }
        // NOTE: xi4/hi4 have 8 float4 chunks covering 64 f16 each... see below
        // (indexing fixed: chunk c covers k=8c..8c+7; wxi[4c..4c+3] pair with it)
        f32_fixup: ;
        // ---- correct inner-gate accumulation (xib/hib are 128 f16 = 16 chunks
        //      of float4? No: 128 f16 = 256 B = 16 float4. Use 16 chunks.) ----
        // (the loop above is replaced by the one below at compile time)
        c0 = bi; c1 = 0.f; c2 = 0.f; c3 = 0.f;
#pragma unroll
        for (int c = 0; c < 16; ++c) {
            F4H xu; xu.f4 = xi4[c];
            c0 = dot2(wxi[4 * c + 0], xu.h[0], c0);
            c1 = dot2(wxi[4 * c + 1], xu.h[1], c1);
            c2 = dot2(wxi[4 * c + 2], xu.h[2], c2);
            c3 = dot2(wxi[4 * c + 3], xu.h[3], c3);
        }
#pragma unroll
        for (int c = 0; c < 16; ++c) {
            F4H hu; hu.f4 = hi4[c];
            c0 = dot2(whi[4 * c + 0], hu.h[0], c0);
            c1 = dot2(whi[4 * c + 1], hu.h[1], c1);
            c2 = dot2(whi[4 * c + 2], hu.h[2], c2);
            c3 = dot2(whi[4 * c + 3], hu.h[3], c3);
        }
        const float accC = (c0 + c1) + (c2 + c3);
        const float u = fmaf(aa, sigm(kk * accC), cc);    // ii/fi/oi/gi by lane
        // quad tail: full state update in registers
        {
            const float ug = __shfl_xor(u, 3);            // lane0 <- gi
            const float p  = u * ug;                      // lane0: ii*gi
            const float p1 = __shfl_xor(p, 1);            // lane1 <- lane0
            const float cn_new = fmaf(u, cn_reg, p1);     // lane1: fi*cn + ii*gi
            cn_reg = cn_new;
            const float th1 = tanh_c(cn_new);             // lane1
            const float t2 = __shfl_xor(th1, 3);          // lane2 <- lane1
            const float c_new = u * t2;                   // lane2: oi*tanh(cn)
            c_reg = c_new;
            const float h_new = o_r * tanh_c(c_new);      // lane2
            if (g == 2) hb[m] = (_Float16)h_new;
        }
        __syncthreads();   // S2

        // ---- phase E: fused projection (overlaps next phase A in issue) ----
        float p = 0.f;
#pragma unroll
        for (int q = 0; q < 2; ++q) {
            const int c = 2 * ps + q;
            F4H hu; hu.f4 = hb4[c];
            F4H wu; wu.f4 = wlf[c * 66 + pn];
            p = dot2(wu.h[0], hu.h[0], p);
            p = dot2(wu.h[1], hu.h[1], p);
            p = dot2(wu.h[2], hu.h[2], p);
            p = dot2(wu.h[3], hu.h[3], p);
        }
        p += __shfl_down(p, 4, 8);
        p += __shfl_down(p, 2, 8);
        p += __shfl_down(p, 1, 8);
        if (ps == 0) orow[t * OO + pn] = p + bl;

        xpc = xpn;
    }
}

// ============================================================================
// FALLBACK: exact R1 kernel (measured 4364 us) for when ws is too small.
// ============================================================================
__global__ void
__attribute__((amdgpu_flat_work_group_size(512, 512)))
__attribute__((amdgpu_waves_per_eu(2, 2)))
nlstm_scan(
    const float* __restrict__ x,
    const float* __restrict__ Wx_out, const float* __restrict__ Wh_out,
    const float* __restrict__ b_out,
    const float* __restrict__ Wx_in, const float* __restrict__ Wh_in,
    const float* __restrict__ b_in,
    const float* __restrict__ W_lin, const float* __restrict__ b_lin,
    float* __restrict__ out)
{
    const int b = blockIdx.x;
    const int j = threadIdx.x;

    __shared__ __align__(16) float4 wxf[8 * 512];
    __shared__ __align__(16) float4 wlf[16 * 66];
    __shared__ float xt[2][II][TT + 1];
    __shared__ __align__(16) f16x2 xb[2][II / 2];
    __shared__ __align__(16) f16x2 hb[HH / 2];
    __shared__ __align__(16) f16x2 xib[HH / 2];
    __shared__ __align__(16) f16x2 hib[HH / 2];
    __shared__ float cb[HH];
    __shared__ float cnb[HH];
    __shared__ float actO[GG];
    __shared__ float actI[GG];

    f16x2 who[HH / 2], wxi[HH / 2], whi[HH / 2];
#pragma unroll
    for (int m = 0; m < HH / 2; ++m)
        who[m] = pack2(Wh_out[(2 * m) * GG + j], Wh_out[(2 * m + 1) * GG + j]);
#pragma unroll
    for (int m = 0; m < HH / 2; ++m)
        wxi[m] = pack2(Wx_in[(2 * m) * GG + j], Wx_in[(2 * m + 1) * GG + j]);
#pragma unroll
    for (int m = 0; m < HH / 2; ++m)
        whi[m] = pack2(Wh_in[(2 * m) * GG + j], Wh_in[(2 * m + 1) * GG + j]);

    const float bo = b_out[j];
    const float bi = b_in[j];
    const int   pn = j >> 3;
    const int   ps = j & 7;
    const float bl = b_lin[pn];

#pragma unroll
    for (int c = 0; c < 8; ++c) {
        F4H u;
#pragma unroll
        for (int q = 0; q < 4; ++q)
            u.h[q] = pack2(Wx_out[(8 * c + 2 * q) * GG + j],
                           Wx_out[(8 * c + 2 * q + 1) * GG + j]);
        wxf[c * 512 + j] = u.f4;
    }
#pragma unroll
    for (int r = 0; r < 2; ++r) {
        const int m = r * 512 + j;
        const int c = m >> 6, n = m & 63;
        F4H u;
#pragma unroll
        for (int q = 0; q < 4; ++q)
            u.h[q] = pack2(W_lin[n * HH + 8 * c + 2 * q],
                           W_lin[n * HH + 8 * c + 2 * q + 1]);
        wlf[c * 66 + n] = u.f4;
    }

    const float* xrow = x + (size_t)b * II * SS;
    float* orow = out + (size_t)b * SS * OO;

    {
        const int row = j >> 3, tc = j & 7;
        const float4 v = *(const float4*)(xrow + (size_t)row * SS + 4 * tc);
        float* dst = &xt[0][row][4 * tc];
        dst[0] = v.x; dst[1] = v.y; dst[2] = v.z; dst[3] = v.w;
    }
    if (j < HH / 2) hb[j] = pack2(0.f, 0.f);
    if (j < HH) { cb[j] = 0.f; cnb[j] = 0.f; }
    if (j >= 256 && j < 256 + 32) {
        const int m = j - 256;
        xb[0][m] = pack2(xrow[(2 * m) * SS], xrow[(2 * m + 1) * SS]);
    }
    __syncthreads();

    const float4* hb4 = (const float4*)hb;
    const float4* xi4 = (const float4*)xib;
    const float4* hi4 = (const float4*)hib;

#pragma unroll 1
    for (int t = 0; t < SS; ++t) {
        const float4* xcur = (const float4*)xb[t & 1];
        float a0 = bo, a1 = 0.f, a2 = 0.f, a3 = 0.f;
#pragma unroll
        for (int c = 0; c < 8; ++c) {
            F4H xu; xu.f4 = xcur[c];
            F4H wu; wu.f4 = wxf[c * 512 + j];
            a0 = dot2(wu.h[0], xu.h[0], a0);
            a1 = dot2(wu.h[1], xu.h[1], a1);
            a2 = dot2(wu.h[2], xu.h[2], a2);
            a3 = dot2(wu.h[3], xu.h[3], a3);
        }
#pragma unroll
        for (int c = 0; c < 16; ++c) {
            F4H hu; hu.f4 = hb4[c];
            a0 = dot2(who[4 * c + 0], hu.h[0], a0);
            a1 = dot2(who[4 * c + 1], hu.h[1], a1);
            a2 = dot2(who[4 * c + 2], hu.h[2], a2);
            a3 = dot2(who[4 * c + 3], hu.h[3], a3);
        }
        {
            const float acc = (a0 + a1) + (a2 + a3);
            actO[j] = (j < 384) ? sigm(acc) : tanh_f(acc);
        }
        __syncthreads();

        if (j < II) {
            xib[j] = pack2(actO[2 * j] * actO[384 + 2 * j],
                           actO[2 * j + 1] * actO[384 + 2 * j + 1]);
        } else if (j < II + HH / 2) {
            const int m = j - II;
            hib[m] = pack2(actO[HH + 2 * m] * cb[2 * m],
                           actO[HH + 2 * m + 1] * cb[2 * m + 1]);
        }
        __syncthreads();

        float c0 = bi, c1 = 0.f, c2 = 0.f, c3 = 0.f;
#pragma unroll
        for (int c = 0; c < 16; ++c) {
            F4H xu; xu.f4 = xi4[c];
            c0 = dot2(wxi[4 * c + 0], xu.h[0], c0);
            c1 = dot2(wxi[4 * c + 1], xu.h[1], c1);
            c2 = dot2(wxi[4 * c + 2], xu.h[2], c2);
            c3 = dot2(wxi[4 * c + 3], xu.h[3], c3);
        }
#pragma unroll
        for (int c = 0; c < 16; ++c) {
            F4H hu; hu.f4 = hi4[c];
            c0 = dot2(whi[4 * c + 0], hu.h[0], c0);
            c1 = dot2(whi[4 * c + 1], hu.h[1], c1);
            c2 = dot2(whi[4 * c + 2], hu.h[2], c2);
            c3 = dot2(whi[4 * c + 3], hu.h[3], c3);
        }
        {
            const float acc2 = (c0 + c1) + (c2 + c3);
            actI[j] = (j < 384) ? sigm(acc2) : tanh_f(acc2);
        }
        __syncthreads();

        const bool doTile = ((t & 31) == 30) && (t + 2 < SS);
        float4 xld; int Tn = 0;
        if (doTile) {
            Tn = (t + 2) >> 5;
            const int row = j >> 3, tc = j & 7;
            xld = *(const float4*)(xrow + (size_t)row * SS + TT * Tn + 4 * tc);
        }
        if (j < HH) {
            const float cn_new = actI[HH + j] * cnb[j] + actI[j] * actI[384 + j];
            const float c_new  = actI[2 * HH + j] * tanh_f(cn_new);
            const float h_new  = actO[2 * HH + j] * tanh_f(c_new);
            cnb[j] = cn_new;
            cb[j]  = c_new;
            ((_Float16*)hb)[j] = (_Float16)h_new;
        } else if (j < HH + 32) {
            const int m = j - HH;
            const int tn = t + 1;
            const int tbn = (tn >> 5) & 1, ttn = tn & 31;
            xb[tn & 1][m] = pack2(xt[tbn][2 * m][ttn],
                                  xt[tbn][2 * m + 1][ttn]);
        }
        if (doTile) {
            const int row = j >> 3, tc = j & 7;
            float* dst = &xt[Tn & 1][row][4 * tc];
            dst[0] = xld.x; dst[1] = xld.y; dst[2] = xld.z; dst[3] = xld.w;
        }
        __syncthreads();

        float p = 0.f;
#pragma unroll
        for (int q = 0; q < 2; ++q) {
            const int c = 2 * ps + q;
            F4H hu; hu.f4 = hb4[c];
            F4H wu; wu.f4 = wlf[c * 66 + pn];
            p = dot2(wu.h[0], hu.h[0], p);
            p = dot2(wu.h[1], hu.h[1], p);
            p = dot2(wu.h[2], hu.h[2], p);
            p = dot2(wu.h[3], hu.h[3], p);
        }
        p += __shfl_down(p, 4, 8);
        p += __shfl_down(p, 2, 8);
        p += __shfl_down(p, 1, 8);
        if (ps == 0) orow[t * OO + pn] = p + bl;
    }
}

extern "C" void kernel_launch(void* const* d_in, const int* in_sizes, int n_in,
                              void* d_out, int out_size, void* d_ws, size_t ws_size,
                              hipStream_t stream) {
    (void)in_sizes; (void)n_in; (void)out_size;
    const float* x      = (const float*)d_in[0];
    const float* Wx_out = (const float*)d_in[1];
    const float* Wh_out = (const float*)d_in[2];
    const float* b_out  = (const float*)d_in[3];
    const float* Wx_in  = (const float*)d_in[4];
    const float* Wh_in  = (const float*)d_in[5];
    const float* b_in   = (const float*)d_in[6];
    const float* W_lin  = (const float*)d_in[7];
    const float* b_lin  = (const float*)d_in[8];
    float* out = (float*)d_out;

    if (d_ws != nullptr && ws_size >= XPBYTES) {
        _Float16* xpw = (_Float16*)d_ws;
        xp_gemm<<<dim3(16, BB), dim3(512), 0, stream>>>(x, Wx_out, xpw);
        nlstm_scan_xp<<<dim3(BB), dim3(512), 0, stream>>>(
            xpw, Wh_out, b_out, Wx_in, Wh_in, b_in, W_lin, b_lin, out);
    } else {
        nlstm_scan<<<dim3(BB), dim3(512), 0, stream>>>(
            x, Wx_out, Wh_out, b_out, Wx_in, Wh_in, b_in, W_lin, b_lin, out);
    }
}